// Round 12
// baseline (331.730 us; speedup 1.0000x reference)
//
#include <hip/hip_runtime.h>
#include <math.h>

// Problem constants
#define NTOK 4096
#define PCH  128
#define ICH  256
#define OCH  128
#define NB   2
#define SCALEF 0.08838834764831845f   // 1/sqrt(128)

typedef __bf16 bf16_t;
typedef __attribute__((ext_vector_type(8))) __bf16 bf16x8;
typedef __attribute__((ext_vector_type(4))) __bf16 bf16x4;
typedef __attribute__((ext_vector_type(4))) float floatx4;

#define LDK 136   // padded row length (bf16) for k=128 tiles
#define LDJ 72    // padded row length (bf16) for j=64 Es tiles

// ---------------------------------------------------------------------------
// K-1: zero fus (8 MB) + zsum buffers (64 KB) — contiguous at ws start.
// ---------------------------------------------------------------------------
__global__ __launch_bounds__(256) void zero_kernel(float4* __restrict__ p)
{
    p[(size_t)blockIdx.x * 256 + threadIdx.x] = float4{0.f, 0.f, 0.f, 0.f};
}

// ---------------------------------------------------------------------------
// K0: pack pf -> pfC (bf16 channel-major) + pfT (bf16 token-major)
// ---------------------------------------------------------------------------
__global__ __launch_bounds__(256) void pack_pf(const float* __restrict__ pf,
                                               bf16_t* __restrict__ pfC,
                                               bf16_t* __restrict__ pfT)
{
    __shared__ float Ls[64][65];
    const int t = threadIdx.x;
    const int n0 = blockIdx.x * 64, d0 = blockIdx.y * 64, b = blockIdx.z;
    const float* src = pf + ((size_t)(b * PCH + d0)) * NTOK + n0;
#pragma unroll
    for (int p = 0; p < 4; p++) {
        int d = p * 16 + (t >> 4), c = t & 15;
        float4 v = *(const float4*)&src[d * NTOK + c * 4];
        Ls[d][c * 4 + 0] = v.x; Ls[d][c * 4 + 1] = v.y;
        Ls[d][c * 4 + 2] = v.z; Ls[d][c * 4 + 3] = v.w;
        bf16x4 o = { (bf16_t)v.x, (bf16_t)v.y, (bf16_t)v.z, (bf16_t)v.w };
        *(bf16x4*)&pfC[((size_t)(b * PCH + d0 + d)) * NTOK + n0 + c * 4] = o;
    }
    __syncthreads();
#pragma unroll
    for (int p = 0; p < 2; p++) {
        int n = p * 32 + (t >> 3), c = t & 7;
        bf16x8 o;
#pragma unroll
        for (int k = 0; k < 8; k++) o[k] = (bf16_t)Ls[c * 8 + k][n];
        *(bf16x8*)&pfT[((size_t)(b * NTOK + n0 + n)) * PCH + d0 + c * 8] = o;
    }
}

// ---------------------------------------------------------------------------
// K1: fc2 — ri[b][p][n] = sum_c img[b][c][n]*w[p][c] + bias[p]
// ---------------------------------------------------------------------------
__global__ __launch_bounds__(256) void fc2_kernel(const float* __restrict__ img,
                                                  const float* __restrict__ w,
                                                  const float* __restrict__ bias,
                                                  bf16_t* __restrict__ riC,
                                                  bf16_t* __restrict__ riT)
{
    const int b = blockIdx.z, t = threadIdx.x;
    const int n = blockIdx.x * 64 + (t & 63);
    const int pbase = blockIdx.y * 32 + (t >> 6) * 8;   // wave-uniform
    const float* imgb = img + (size_t)b * ICH * NTOK + n;

    float acc[8];
#pragma unroll
    for (int pp = 0; pp < 8; pp++) acc[pp] = bias[pbase + pp];

    for (int c = 0; c < ICH; c += 4) {
        float v0 = imgb[(c + 0) * NTOK];
        float v1 = imgb[(c + 1) * NTOK];
        float v2 = imgb[(c + 2) * NTOK];
        float v3 = imgb[(c + 3) * NTOK];
#pragma unroll
        for (int pp = 0; pp < 8; pp++) {
            float4 wv = *(const float4*)&w[(pbase + pp) * ICH + c];
            acc[pp] += wv.x * v0 + wv.y * v1 + wv.z * v2 + wv.w * v3;
        }
    }

#pragma unroll
    for (int pp = 0; pp < 8; pp++)
        riC[((size_t)(b * PCH + pbase + pp)) * NTOK + n] = (bf16_t)acc[pp];
    bf16x8 tv;
#pragma unroll
    for (int pp = 0; pp < 8; pp++) tv[pp] = (bf16_t)acc[pp];
    *(bf16x8*)&riT[((size_t)(b * NTOK + n)) * PCH + pbase] = tv;
}

// ---------------------------------------------------------------------------
// K2: stats v5 (proven ~43us) — one pass over E = exp(scale * pf_i . ri_j):
//   zr[i] += sum_j E[i,j],  zc[j] += sum_i E[i,j]
// Direct-global B fragments + raw s_barrier pacing; zcol via LDS accumulator.
// ---------------------------------------------------------------------------
__global__ __launch_bounds__(256, 4) void stats_mfma(const bf16_t* __restrict__ pfT,
                                                     const bf16_t* __restrict__ riT,
                                                     float* __restrict__ zr,
                                                     float* __restrict__ zc)
{
    __shared__ bf16_t As[64 * LDK];
    __shared__ float zacc[1024];
    const int b = blockIdx.y, t = threadIdx.x;
    const int js = blockIdx.z;
    const bf16_t* At = pfT + (size_t)b * NTOK * PCH;
    const bf16_t* Bt = riT + (size_t)b * NTOK * PCH;
    float* zrow = zr + (size_t)b * NTOK;
    float* zcol = zc + (size_t)b * NTOK;
    const int lane = t & 63, w = t >> 6, tx = lane & 15, q = lane >> 4;
    const int i0 = blockIdx.x * 64;
    const int jbase = js * 1024;
    const int sr = t >> 4, sc = t & 15;
    const bf16_t* Brow = Bt + (size_t)(jbase + w * 16 + tx) * PCH;

    bf16x8 bcur[4];
#pragma unroll
    for (int s = 0; s < 4; s++)
        bcur[s] = *(const bf16x8*)&Brow[s * 32 + q * 8];
#pragma unroll
    for (int p = 0; p < 4; p++) {
        int i = p * 16 + sr;
        *(uint4*)&As[i * LDK + sc * 8] = *(const uint4*)&At[((size_t)(i0 + i)) * PCH + sc * 8];
    }
    __syncthreads();
    bf16x8 af[4][4];
#pragma unroll
    for (int mt = 0; mt < 4; mt++)
#pragma unroll
        for (int s = 0; s < 4; s++)
            af[mt][s] = *(bf16x8*)&As[(mt * 16 + tx) * LDK + s * 32 + q * 8];

    float racc[4] = {0.f, 0.f, 0.f, 0.f};
    for (int jt = 0; jt < 16; jt++) {
        __builtin_amdgcn_s_barrier();            // pacing only
        floatx4 sacc[4];
#pragma unroll
        for (int mt = 0; mt < 4; mt++) {
            sacc[mt] = (floatx4){0.f, 0.f, 0.f, 0.f};
#pragma unroll
            for (int s = 0; s < 4; s++)
                sacc[mt] = __builtin_amdgcn_mfma_f32_16x16x32_bf16(bcur[s], af[mt][s], sacc[mt], 0, 0, 0);
        }
        if (jt < 15) {
            const bf16_t* bn = Brow + (size_t)(jt + 1) * 64 * PCH;
#pragma unroll
            for (int s = 0; s < 4; s++)
                bcur[s] = *(const bf16x8*)&bn[s * 32 + q * 8];
        }

        float ctmp[4] = {0.f, 0.f, 0.f, 0.f};
#pragma unroll
        for (int mt = 0; mt < 4; mt++)
#pragma unroll
            for (int r = 0; r < 4; r++) {
                float e = __expf(sacc[mt][r] * SCALEF);
                racc[mt] += e;
                ctmp[r]  += e;
            }
#pragma unroll
        for (int r = 0; r < 4; r++) {
            float v = ctmp[r];
            v += __shfl_xor(v, 1); v += __shfl_xor(v, 2);
            v += __shfl_xor(v, 4); v += __shfl_xor(v, 8);
            if (tx == 0) zacc[jt * 64 + w * 16 + q * 4 + r] = v;
        }
    }
#pragma unroll
    for (int mt = 0; mt < 4; mt++) {
        float v = racc[mt];
        v += __shfl_xor(v, 16);
        v += __shfl_xor(v, 32);
        if (q == 0) atomicAdd(&zrow[i0 + mt * 16 + tx], v);
    }
    __syncthreads();
#pragma unroll
    for (int k = 0; k < 4; k++)
        atomicAdd(&zcol[jbase + k * 256 + t], zacc[k * 256 + t]);
}

// ---------------------------------------------------------------------------
// K3: attn — EXACT R10 body (82.5us proven; two pipelining attempts both
// spilled). ONLY change: __launch_bounds__(256,4) — grid is exactly 4
// blocks/CU and LDS 35840*4=143KB fits, VGPR 84<=128, so allowing 4 resident
// removes the 3-resident straggler batch (measured occupancy 26.6% ~ 2.1
// blocks/CU average = tail-limited).
// ---------------------------------------------------------------------------
__global__ __launch_bounds__(256, 4) void attn_mfma(const bf16_t* __restrict__ pfT,
                                                    const bf16_t* __restrict__ riT,
                                                    const bf16_t* __restrict__ pfC,
                                                    const bf16_t* __restrict__ riC,
                                                    const float* __restrict__ zrsum,
                                                    const float* __restrict__ zcsum,
                                                    float* __restrict__ fus)
{
    __shared__ bf16_t As[64 * LDK];
    __shared__ bf16_t Es[2][64 * LDJ];
    const int b = blockIdx.y, t = threadIdx.x;
    const int mode = blockIdx.z >> 2, js = blockIdx.z & 3;
    const bf16_t* At = (mode == 0 ? pfT : riT) + (size_t)b * NTOK * PCH;
    const bf16_t* Bt = (mode == 0 ? riT : pfT) + (size_t)b * NTOK * PCH;
    const bf16_t* Vc = (mode == 0 ? pfC : riC) + (size_t)b * PCH * NTOK;
    const float* wsum = (mode == 0 ? zcsum : zrsum) + (size_t)b * NTOK;
    const int lane = t & 63, w = t >> 6, tx = lane & 15, q = lane >> 4;
    const int i0 = blockIdx.x * 64;
    const int jbase = js * 1024;
    const int sr = t >> 4, sc = t & 15;
    const bf16_t* Brow = Bt + (size_t)(jbase + w * 16 + tx) * PCH;

    bf16x8 bcur[4];
#pragma unroll
    for (int s = 0; s < 4; s++)
        bcur[s] = *(const bf16x8*)&Brow[s * 32 + q * 8];
    bf16x8 vcur[2][2];
#pragma unroll
    for (int nt = 0; nt < 2; nt++)
#pragma unroll
        for (int s = 0; s < 2; s++)
            vcur[nt][s] = *(const bf16x8*)&Vc[((size_t)(w * 32 + nt * 16 + tx)) * NTOK + jbase + s * 32 + q * 8];
    float4 wv = *(const float4*)&wsum[jbase + w * 16 + q * 4];
    float4 wr4 = {1.f / wv.x, 1.f / wv.y, 1.f / wv.z, 1.f / wv.w};

#pragma unroll
    for (int p = 0; p < 4; p++) {
        int i = p * 16 + sr;
        *(uint4*)&As[i * LDK + sc * 8] = *(const uint4*)&At[((size_t)(i0 + i)) * PCH + sc * 8];
    }
    __syncthreads();
    bf16x8 af[4][4];
#pragma unroll
    for (int mt = 0; mt < 4; mt++)
#pragma unroll
        for (int s = 0; s < 4; s++)
            af[mt][s] = *(bf16x8*)&As[(mt * 16 + tx) * LDK + s * 32 + q * 8];

    floatx4 outacc[4][2];
#pragma unroll
    for (int mt = 0; mt < 4; mt++)
#pragma unroll
        for (int nt = 0; nt < 2; nt++)
            outacc[mt][nt] = (floatx4){0.f, 0.f, 0.f, 0.f};

    for (int jt = 0; jt < 16; jt++) {
        const int cur = jt & 1;
        const int j0 = jbase + jt * 64;

        floatx4 sacc[4];
#pragma unroll
        for (int mt = 0; mt < 4; mt++) {
            sacc[mt] = (floatx4){0.f, 0.f, 0.f, 0.f};
#pragma unroll
            for (int s = 0; s < 4; s++)
                sacc[mt] = __builtin_amdgcn_mfma_f32_16x16x32_bf16(bcur[s], af[mt][s], sacc[mt], 0, 0, 0);
        }
        if (jt < 15) {
            const bf16_t* bn = Brow + (size_t)(jt + 1) * 64 * PCH;
#pragma unroll
            for (int s = 0; s < 4; s++)
                bcur[s] = *(const bf16x8*)&bn[s * 32 + q * 8];
        }

#pragma unroll
        for (int mt = 0; mt < 4; mt++) {
            bf16x4 ev;
#pragma unroll
            for (int r = 0; r < 4; r++)
                ev[r] = (bf16_t)(__expf(sacc[mt][r] * SCALEF) * ((const float*)&wr4)[r]);
            *(bf16x4*)&Es[cur][(mt * 16 + tx) * LDJ + w * 16 + q * 4] = ev;
        }
        float4 wnv;
        if (jt < 15)
            wnv = *(const float4*)&wsum[j0 + 64 + w * 16 + q * 4];

        __syncthreads();

        bf16x8 ef[4][2];
#pragma unroll
        for (int mt = 0; mt < 4; mt++)
#pragma unroll
            for (int s = 0; s < 2; s++)
                ef[mt][s] = *(bf16x8*)&Es[cur][(mt * 16 + tx) * LDJ + s * 32 + q * 8];
#pragma unroll
        for (int nt = 0; nt < 2; nt++)
#pragma unroll
            for (int s = 0; s < 2; s++)
#pragma unroll
                for (int mt = 0; mt < 4; mt++)
                    outacc[mt][nt] = __builtin_amdgcn_mfma_f32_16x16x32_bf16(ef[mt][s], vcur[nt][s], outacc[mt][nt], 0, 0, 0);

        if (jt < 15) {
#pragma unroll
            for (int nt = 0; nt < 2; nt++)
#pragma unroll
                for (int s = 0; s < 2; s++)
                    vcur[nt][s] = *(const bf16x8*)&Vc[((size_t)(w * 32 + nt * 16 + tx)) * NTOK + (j0 + 64) + s * 32 + q * 8];
            wr4 = (float4){1.f / wnv.x, 1.f / wnv.y, 1.f / wnv.z, 1.f / wnv.w};
        }
    }

    float* fo = fus + ((size_t)(b * NTOK + i0)) * 256 + mode * 128 + w * 32;
#pragma unroll
    for (int mt = 0; mt < 4; mt++)
#pragma unroll
        for (int nt = 0; nt < 2; nt++)
#pragma unroll
            for (int r = 0; r < 4; r++)
                atomicAdd(&fo[(mt * 16 + q * 4 + r) * 256 + nt * 16 + tx], outacc[mt][nt][r]);
}

// ---------------------------------------------------------------------------
// K4: 1x1 conv (256 -> 128) + BN(eval) + ReLU.
// ---------------------------------------------------------------------------
__global__ __launch_bounds__(256) void conv_kernel(const float* __restrict__ fus,
                                                   const float* __restrict__ cw,
                                                   const float* __restrict__ cb,
                                                   const float* __restrict__ g,
                                                   const float* __restrict__ be,
                                                   const float* __restrict__ mu,
                                                   const float* __restrict__ var,
                                                   float* __restrict__ out)
{
    __shared__ float Ls[64][260];
    const int b = blockIdx.z, t = threadIdx.x;
    const int n0 = blockIdx.x * 64;
    const int obase = blockIdx.y * 32 + (t >> 6) * 8;   // wave-uniform

    const float4* src = (const float4*)(fus + ((size_t)(b * NTOK + n0)) * 256);
#pragma unroll
    for (int it = 0; it < 16; it++) {
        int row = it * 4 + (t >> 6);
        float4 v = src[row * 64 + (t & 63)];
        *(float4*)&Ls[row][(t & 63) * 4] = v;
    }
    __syncthreads();

    const int n = t & 63;
    float acc[8] = {};
    for (int c = 0; c < 256; c += 4) {
        float4 v = *(const float4*)&Ls[n][c];
#pragma unroll
        for (int oo = 0; oo < 8; oo++) {
            float4 wv = *(const float4*)&cw[(obase + oo) * 256 + c];
            acc[oo] += wv.x * v.x + wv.y * v.y + wv.z * v.z + wv.w * v.w;
        }
    }
#pragma unroll
    for (int oo = 0; oo < 8; oo++) {
        const int o = obase + oo;
        const float s  = g[o] * rsqrtf(var[o] + 1e-5f);
        const float b0 = be[o] + (cb[o] - mu[o]) * s;
        float y = acc[oo] * s + b0;
        out[((size_t)(b * OCH + o)) * NTOK + n0 + n] = fmaxf(y, 0.f);
    }
}

// ---------------------------------------------------------------------------
extern "C" void kernel_launch(void* const* d_in, const int* in_sizes, int n_in,
                              void* d_out, int out_size, void* d_ws, size_t ws_size,
                              hipStream_t stream)
{
    const float* pf   = (const float*)d_in[0];
    const float* img  = (const float*)d_in[1];
    const float* fc2w = (const float*)d_in[2];
    const float* fc2b = (const float*)d_in[3];
    const float* cw   = (const float*)d_in[4];
    const float* cb   = (const float*)d_in[5];
    const float* g    = (const float*)d_in[6];
    const float* be   = (const float*)d_in[7];
    const float* mu   = (const float*)d_in[8];
    const float* var  = (const float*)d_in[9];
    float* out = (float*)d_out;

    // ws layout: EXACTLY the proven footprint (16,842,752 B).
    float* fus   = (float*)d_ws;                              // 8 MB
    float* zrsum = fus + (size_t)NB * NTOK * 256;             // 32 KB
    float* zcsum = zrsum + NB * NTOK;                         // 32 KB
    bf16_t* pfC = (bf16_t*)(zcsum + NB * NTOK);               // 2 MB
    bf16_t* pfT = pfC + (size_t)NB * PCH * NTOK;              // 2 MB
    bf16_t* riC = pfT + (size_t)NB * NTOK * PCH;              // 2 MB
    bf16_t* riT = riC + (size_t)NB * PCH * NTOK;              // 2 MB

    // zero fus + zsums: (2*4096*256 + 2*2*4096) floats = 528384 float4
    zero_kernel<<<dim3(2064), 256, 0, stream>>>((float4*)d_ws);
    pack_pf    <<<dim3(64, 2, NB),  256, 0, stream>>>(pf, pfC, pfT);
    fc2_kernel <<<dim3(64, 4, NB),  256, 0, stream>>>(img, fc2w, fc2b, riC, riT);
    stats_mfma <<<dim3(64, NB, 4),  256, 0, stream>>>(pfT, riT, zrsum, zcsum);
    attn_mfma  <<<dim3(64, NB, 8),  256, 0, stream>>>(pfT, riT, pfC, riC, zrsum, zcsum, fus);
    conv_kernel<<<dim3(64, 4, NB),  256, 0, stream>>>(fus, cw, cb, g, be, mu, var, out);
}

// Round 13
// 214.107 us; speedup vs baseline: 1.5494x; 1.5494x over previous
//
#include <hip/hip_runtime.h>
#include <math.h>

// Problem constants
#define NTOK 4096
#define PCH  128
#define ICH  256
#define OCH  128
#define NB   2
#define SCALEF 0.08838834764831845f   // 1/sqrt(128)

typedef __bf16 bf16_t;
typedef __attribute__((ext_vector_type(8))) __bf16 bf16x8;
typedef __attribute__((ext_vector_type(4))) __bf16 bf16x4;
typedef __attribute__((ext_vector_type(4))) float floatx4;

#define LDK 136   // padded row length (bf16) for k=128 tiles
#define LDJ 72    // padded row length (bf16) for j=64 Es tiles

// ---------------------------------------------------------------------------
// K-1: zero fus (8 MB) + zsum buffers (64 KB) — contiguous at ws start.
// Runs AFTER fc2 (imgT aliases the fus region and is dead by then).
// ---------------------------------------------------------------------------
__global__ __launch_bounds__(256) void zero_kernel(float4* __restrict__ p)
{
    p[(size_t)blockIdx.x * 256 + threadIdx.x] = float4{0.f, 0.f, 0.f, 0.f};
}

// ---------------------------------------------------------------------------
// K0a: pack pf -> pfC (bf16 channel-major) + pfT (bf16 token-major)
// ---------------------------------------------------------------------------
__global__ __launch_bounds__(256) void pack_pf(const float* __restrict__ pf,
                                               bf16_t* __restrict__ pfC,
                                               bf16_t* __restrict__ pfT)
{
    __shared__ float Ls[64][65];
    const int t = threadIdx.x;
    const int n0 = blockIdx.x * 64, d0 = blockIdx.y * 64, b = blockIdx.z;
    const float* src = pf + ((size_t)(b * PCH + d0)) * NTOK + n0;
#pragma unroll
    for (int p = 0; p < 4; p++) {
        int d = p * 16 + (t >> 4), c = t & 15;
        float4 v = *(const float4*)&src[d * NTOK + c * 4];
        Ls[d][c * 4 + 0] = v.x; Ls[d][c * 4 + 1] = v.y;
        Ls[d][c * 4 + 2] = v.z; Ls[d][c * 4 + 3] = v.w;
        bf16x4 o = { (bf16_t)v.x, (bf16_t)v.y, (bf16_t)v.z, (bf16_t)v.w };
        *(bf16x4*)&pfC[((size_t)(b * PCH + d0 + d)) * NTOK + n0 + c * 4] = o;
    }
    __syncthreads();
#pragma unroll
    for (int p = 0; p < 2; p++) {
        int n = p * 32 + (t >> 3), c = t & 7;
        bf16x8 o;
#pragma unroll
        for (int k = 0; k < 8; k++) o[k] = (bf16_t)Ls[c * 8 + k][n];
        *(bf16x8*)&pfT[((size_t)(b * NTOK + n0 + n)) * PCH + d0 + c * 8] = o;
    }
}

// ---------------------------------------------------------------------------
// K0b: pack img (f32 channel-major [b][c][n]) -> imgT bf16 token-major
// imgT[(b*NTOK+n)*ICH + c]. Same transpose structure as pack_pf.
// ---------------------------------------------------------------------------
__global__ __launch_bounds__(256) void pack_img(const float* __restrict__ img,
                                                bf16_t* __restrict__ imgT)
{
    __shared__ float Ls[64][65];
    const int t = threadIdx.x;
    const int n0 = blockIdx.x * 64, c0 = blockIdx.y * 64, b = blockIdx.z;
    const float* src = img + ((size_t)(b * ICH + c0)) * NTOK + n0;
#pragma unroll
    for (int p = 0; p < 4; p++) {
        int d = p * 16 + (t >> 4), c = t & 15;
        float4 v = *(const float4*)&src[d * NTOK + c * 4];
        Ls[d][c * 4 + 0] = v.x; Ls[d][c * 4 + 1] = v.y;
        Ls[d][c * 4 + 2] = v.z; Ls[d][c * 4 + 3] = v.w;
    }
    __syncthreads();
#pragma unroll
    for (int p = 0; p < 2; p++) {
        int n = p * 32 + (t >> 3), c = t & 7;
        bf16x8 o;
#pragma unroll
        for (int k = 0; k < 8; k++) o[k] = (bf16_t)Ls[c * 8 + k][n];
        *(bf16x8*)&imgT[((size_t)(b * NTOK + n0 + n)) * ICH + c0 + c * 8] = o;
    }
}

// ---------------------------------------------------------------------------
// K1: fc2 v3 (MFMA) — ri[p][n] = sum_c w[p][c]*img[c][n] + bias[p]
// a-frags = w rows (f32 gather + cvt), b-frags = imgT token rows (direct).
// LDS-free, barrier-free. Wave: 16 tokens x 64 p. D[m=p: q*4+r, n=token: tx].
// Emits riC (channel-major) + riT (token-major).
// ---------------------------------------------------------------------------
__global__ __launch_bounds__(256) void fc2_mfma(const bf16_t* __restrict__ imgT,
                                                const float* __restrict__ w,
                                                const float* __restrict__ bias,
                                                bf16_t* __restrict__ riC,
                                                bf16_t* __restrict__ riT)
{
    const int t = threadIdx.x;
    const int n0 = blockIdx.x * 64, pbase = blockIdx.y * 64, b = blockIdx.z;
    const int lane = t & 63, wv = t >> 6, tx = lane & 15, q = lane >> 4;
    const int n = n0 + wv * 16 + tx;
    const bf16_t* trow = imgT + ((size_t)(b * NTOK + n)) * ICH;

    floatx4 acc[4];
#pragma unroll
    for (int ot = 0; ot < 4; ot++) acc[ot] = (floatx4){0.f, 0.f, 0.f, 0.f};

#pragma unroll
    for (int s = 0; s < 8; s++) {
        bf16x8 bf = *(const bf16x8*)&trow[s * 32 + q * 8];
#pragma unroll
        for (int ot = 0; ot < 4; ot++) {
            const float* wr = w + (size_t)(pbase + ot * 16 + tx) * ICH + s * 32 + q * 8;
            float4 x0 = *(const float4*)wr;
            float4 x1 = *(const float4*)(wr + 4);
            bf16x8 af;
            af[0] = (bf16_t)x0.x; af[1] = (bf16_t)x0.y; af[2] = (bf16_t)x0.z; af[3] = (bf16_t)x0.w;
            af[4] = (bf16_t)x1.x; af[5] = (bf16_t)x1.y; af[6] = (bf16_t)x1.z; af[7] = (bf16_t)x1.w;
            acc[ot] = __builtin_amdgcn_mfma_f32_16x16x32_bf16(af, bf, acc[ot], 0, 0, 0);
        }
    }

#pragma unroll
    for (int ot = 0; ot < 4; ot++) {
        bf16x4 tv;
#pragma unroll
        for (int r = 0; r < 4; r++) {
            const int p = pbase + ot * 16 + q * 4 + r;
            float v = acc[ot][r] + bias[p];
            tv[r] = (bf16_t)v;
            riC[((size_t)(b * PCH + p)) * NTOK + n] = (bf16_t)v;
        }
        *(bf16x4*)&riT[((size_t)(b * NTOK + n)) * PCH + pbase + ot * 16 + q * 4] = tv;
    }
}

// ---------------------------------------------------------------------------
// K2: stats v5 (proven) — one pass over E = exp(scale * pf_i . ri_j):
//   zr[i] += sum_j E[i,j],  zc[j] += sum_i E[i,j]
// Direct-global B fragments + raw s_barrier pacing; zcol via LDS accumulator.
// ---------------------------------------------------------------------------
__global__ __launch_bounds__(256, 4) void stats_mfma(const bf16_t* __restrict__ pfT,
                                                     const bf16_t* __restrict__ riT,
                                                     float* __restrict__ zr,
                                                     float* __restrict__ zc)
{
    __shared__ bf16_t As[64 * LDK];
    __shared__ float zacc[1024];
    const int b = blockIdx.y, t = threadIdx.x;
    const int js = blockIdx.z;
    const bf16_t* At = pfT + (size_t)b * NTOK * PCH;
    const bf16_t* Bt = riT + (size_t)b * NTOK * PCH;
    float* zrow = zr + (size_t)b * NTOK;
    float* zcol = zc + (size_t)b * NTOK;
    const int lane = t & 63, w = t >> 6, tx = lane & 15, q = lane >> 4;
    const int i0 = blockIdx.x * 64;
    const int jbase = js * 1024;
    const int sr = t >> 4, sc = t & 15;
    const bf16_t* Brow = Bt + (size_t)(jbase + w * 16 + tx) * PCH;

    bf16x8 bcur[4];
#pragma unroll
    for (int s = 0; s < 4; s++)
        bcur[s] = *(const bf16x8*)&Brow[s * 32 + q * 8];
#pragma unroll
    for (int p = 0; p < 4; p++) {
        int i = p * 16 + sr;
        *(uint4*)&As[i * LDK + sc * 8] = *(const uint4*)&At[((size_t)(i0 + i)) * PCH + sc * 8];
    }
    __syncthreads();
    bf16x8 af[4][4];
#pragma unroll
    for (int mt = 0; mt < 4; mt++)
#pragma unroll
        for (int s = 0; s < 4; s++)
            af[mt][s] = *(bf16x8*)&As[(mt * 16 + tx) * LDK + s * 32 + q * 8];

    float racc[4] = {0.f, 0.f, 0.f, 0.f};
    for (int jt = 0; jt < 16; jt++) {
        __builtin_amdgcn_s_barrier();            // pacing only
        floatx4 sacc[4];
#pragma unroll
        for (int mt = 0; mt < 4; mt++) {
            sacc[mt] = (floatx4){0.f, 0.f, 0.f, 0.f};
#pragma unroll
            for (int s = 0; s < 4; s++)
                sacc[mt] = __builtin_amdgcn_mfma_f32_16x16x32_bf16(bcur[s], af[mt][s], sacc[mt], 0, 0, 0);
        }
        if (jt < 15) {
            const bf16_t* bn = Brow + (size_t)(jt + 1) * 64 * PCH;
#pragma unroll
            for (int s = 0; s < 4; s++)
                bcur[s] = *(const bf16x8*)&bn[s * 32 + q * 8];
        }

        float ctmp[4] = {0.f, 0.f, 0.f, 0.f};
#pragma unroll
        for (int mt = 0; mt < 4; mt++)
#pragma unroll
            for (int r = 0; r < 4; r++) {
                float e = __expf(sacc[mt][r] * SCALEF);
                racc[mt] += e;
                ctmp[r]  += e;
            }
#pragma unroll
        for (int r = 0; r < 4; r++) {
            float v = ctmp[r];
            v += __shfl_xor(v, 1); v += __shfl_xor(v, 2);
            v += __shfl_xor(v, 4); v += __shfl_xor(v, 8);
            if (tx == 0) zacc[jt * 64 + w * 16 + q * 4 + r] = v;
        }
    }
#pragma unroll
    for (int mt = 0; mt < 4; mt++) {
        float v = racc[mt];
        v += __shfl_xor(v, 16);
        v += __shfl_xor(v, 32);
        if (q == 0) atomicAdd(&zrow[i0 + mt * 16 + tx], v);
    }
    __syncthreads();
#pragma unroll
    for (int k = 0; k < 4; k++)
        atomicAdd(&zcol[jbase + k * 256 + t], zacc[k * 256 + t]);
}

// ---------------------------------------------------------------------------
// K3: attn — EXACT R10 body with (256,3). Proven 82.5us / VGPR 84 / no
// spills. (R9 tile-widen, R11 pipeline, R12 occupancy-4 all spilled.)
// ---------------------------------------------------------------------------
__global__ __launch_bounds__(256, 3) void attn_mfma(const bf16_t* __restrict__ pfT,
                                                    const bf16_t* __restrict__ riT,
                                                    const bf16_t* __restrict__ pfC,
                                                    const bf16_t* __restrict__ riC,
                                                    const float* __restrict__ zrsum,
                                                    const float* __restrict__ zcsum,
                                                    float* __restrict__ fus)
{
    __shared__ bf16_t As[64 * LDK];
    __shared__ bf16_t Es[2][64 * LDJ];
    const int b = blockIdx.y, t = threadIdx.x;
    const int mode = blockIdx.z >> 2, js = blockIdx.z & 3;
    const bf16_t* At = (mode == 0 ? pfT : riT) + (size_t)b * NTOK * PCH;
    const bf16_t* Bt = (mode == 0 ? riT : pfT) + (size_t)b * NTOK * PCH;
    const bf16_t* Vc = (mode == 0 ? pfC : riC) + (size_t)b * PCH * NTOK;
    const float* wsum = (mode == 0 ? zcsum : zrsum) + (size_t)b * NTOK;
    const int lane = t & 63, w = t >> 6, tx = lane & 15, q = lane >> 4;
    const int i0 = blockIdx.x * 64;
    const int jbase = js * 1024;
    const int sr = t >> 4, sc = t & 15;
    const bf16_t* Brow = Bt + (size_t)(jbase + w * 16 + tx) * PCH;

    bf16x8 bcur[4];
#pragma unroll
    for (int s = 0; s < 4; s++)
        bcur[s] = *(const bf16x8*)&Brow[s * 32 + q * 8];
    bf16x8 vcur[2][2];
#pragma unroll
    for (int nt = 0; nt < 2; nt++)
#pragma unroll
        for (int s = 0; s < 2; s++)
            vcur[nt][s] = *(const bf16x8*)&Vc[((size_t)(w * 32 + nt * 16 + tx)) * NTOK + jbase + s * 32 + q * 8];
    float4 wv = *(const float4*)&wsum[jbase + w * 16 + q * 4];
    float4 wr4 = {1.f / wv.x, 1.f / wv.y, 1.f / wv.z, 1.f / wv.w};

#pragma unroll
    for (int p = 0; p < 4; p++) {
        int i = p * 16 + sr;
        *(uint4*)&As[i * LDK + sc * 8] = *(const uint4*)&At[((size_t)(i0 + i)) * PCH + sc * 8];
    }
    __syncthreads();
    bf16x8 af[4][4];
#pragma unroll
    for (int mt = 0; mt < 4; mt++)
#pragma unroll
        for (int s = 0; s < 4; s++)
            af[mt][s] = *(bf16x8*)&As[(mt * 16 + tx) * LDK + s * 32 + q * 8];

    floatx4 outacc[4][2];
#pragma unroll
    for (int mt = 0; mt < 4; mt++)
#pragma unroll
        for (int nt = 0; nt < 2; nt++)
            outacc[mt][nt] = (floatx4){0.f, 0.f, 0.f, 0.f};

    for (int jt = 0; jt < 16; jt++) {
        const int cur = jt & 1;
        const int j0 = jbase + jt * 64;

        floatx4 sacc[4];
#pragma unroll
        for (int mt = 0; mt < 4; mt++) {
            sacc[mt] = (floatx4){0.f, 0.f, 0.f, 0.f};
#pragma unroll
            for (int s = 0; s < 4; s++)
                sacc[mt] = __builtin_amdgcn_mfma_f32_16x16x32_bf16(bcur[s], af[mt][s], sacc[mt], 0, 0, 0);
        }
        if (jt < 15) {
            const bf16_t* bn = Brow + (size_t)(jt + 1) * 64 * PCH;
#pragma unroll
            for (int s = 0; s < 4; s++)
                bcur[s] = *(const bf16x8*)&bn[s * 32 + q * 8];
        }

#pragma unroll
        for (int mt = 0; mt < 4; mt++) {
            bf16x4 ev;
#pragma unroll
            for (int r = 0; r < 4; r++)
                ev[r] = (bf16_t)(__expf(sacc[mt][r] * SCALEF) * ((const float*)&wr4)[r]);
            *(bf16x4*)&Es[cur][(mt * 16 + tx) * LDJ + w * 16 + q * 4] = ev;
        }
        float4 wnv;
        if (jt < 15)
            wnv = *(const float4*)&wsum[j0 + 64 + w * 16 + q * 4];

        __syncthreads();

        bf16x8 ef[4][2];
#pragma unroll
        for (int mt = 0; mt < 4; mt++)
#pragma unroll
            for (int s = 0; s < 2; s++)
                ef[mt][s] = *(bf16x8*)&Es[cur][(mt * 16 + tx) * LDJ + s * 32 + q * 8];
#pragma unroll
        for (int nt = 0; nt < 2; nt++)
#pragma unroll
            for (int s = 0; s < 2; s++)
#pragma unroll
                for (int mt = 0; mt < 4; mt++)
                    outacc[mt][nt] = __builtin_amdgcn_mfma_f32_16x16x32_bf16(ef[mt][s], vcur[nt][s], outacc[mt][nt], 0, 0, 0);

        if (jt < 15) {
#pragma unroll
            for (int nt = 0; nt < 2; nt++)
#pragma unroll
                for (int s = 0; s < 2; s++)
                    vcur[nt][s] = *(const bf16x8*)&Vc[((size_t)(w * 32 + nt * 16 + tx)) * NTOK + (j0 + 64) + s * 32 + q * 8];
            wr4 = (float4){1.f / wnv.x, 1.f / wnv.y, 1.f / wnv.z, 1.f / wnv.w};
        }
    }

    float* fo = fus + ((size_t)(b * NTOK + i0)) * 256 + mode * 128 + w * 32;
#pragma unroll
    for (int mt = 0; mt < 4; mt++)
#pragma unroll
        for (int nt = 0; nt < 2; nt++)
#pragma unroll
            for (int r = 0; r < 4; r++)
                atomicAdd(&fo[(mt * 16 + q * 4 + r) * 256 + nt * 16 + tx], outacc[mt][nt][r]);
}

// ---------------------------------------------------------------------------
// K4: conv v3 (MFMA) — out[o][n] = relu(bn(sum_c cw[o][c]*fus[n][c] + cb))
// fus is token-major f32 -> direct fragment loads + cvt. LDS-free,
// barrier-free. Wave: 16 tokens x 64 o. D[m=o: q*4+r, n=token: tx].
// ---------------------------------------------------------------------------
__global__ __launch_bounds__(256) void conv_mfma(const float* __restrict__ fus,
                                                 const float* __restrict__ cw,
                                                 const float* __restrict__ cb,
                                                 const float* __restrict__ g,
                                                 const float* __restrict__ be,
                                                 const float* __restrict__ mu,
                                                 const float* __restrict__ var,
                                                 float* __restrict__ out)
{
    const int t = threadIdx.x;
    const int n0 = blockIdx.x * 64, obase = blockIdx.y * 64, b = blockIdx.z;
    const int lane = t & 63, wv = t >> 6, tx = lane & 15, q = lane >> 4;
    const int n = n0 + wv * 16 + tx;
    const float* frow = fus + ((size_t)(b * NTOK + n)) * 256;

    floatx4 acc[4];
#pragma unroll
    for (int ot = 0; ot < 4; ot++) acc[ot] = (floatx4){0.f, 0.f, 0.f, 0.f};

#pragma unroll
    for (int s = 0; s < 8; s++) {
        float4 f0 = *(const float4*)&frow[s * 32 + q * 8];
        float4 f1 = *(const float4*)&frow[s * 32 + q * 8 + 4];
        bf16x8 bf;
        bf[0] = (bf16_t)f0.x; bf[1] = (bf16_t)f0.y; bf[2] = (bf16_t)f0.z; bf[3] = (bf16_t)f0.w;
        bf[4] = (bf16_t)f1.x; bf[5] = (bf16_t)f1.y; bf[6] = (bf16_t)f1.z; bf[7] = (bf16_t)f1.w;
#pragma unroll
        for (int ot = 0; ot < 4; ot++) {
            const float* wr = cw + (size_t)(obase + ot * 16 + tx) * 256 + s * 32 + q * 8;
            float4 x0 = *(const float4*)wr;
            float4 x1 = *(const float4*)(wr + 4);
            bf16x8 af;
            af[0] = (bf16_t)x0.x; af[1] = (bf16_t)x0.y; af[2] = (bf16_t)x0.z; af[3] = (bf16_t)x0.w;
            af[4] = (bf16_t)x1.x; af[5] = (bf16_t)x1.y; af[6] = (bf16_t)x1.z; af[7] = (bf16_t)x1.w;
            acc[ot] = __builtin_amdgcn_mfma_f32_16x16x32_bf16(af, bf, acc[ot], 0, 0, 0);
        }
    }

#pragma unroll
    for (int ot = 0; ot < 4; ot++)
#pragma unroll
        for (int r = 0; r < 4; r++) {
            const int o = obase + ot * 16 + q * 4 + r;
            const float sc = g[o] * rsqrtf(var[o] + 1e-5f);
            const float b0 = be[o] + (cb[o] - mu[o]) * sc;
            float y = acc[ot][r] * sc + b0;
            out[((size_t)(b * OCH + o)) * NTOK + n] = fmaxf(y, 0.f);
        }
}

// ---------------------------------------------------------------------------
extern "C" void kernel_launch(void* const* d_in, const int* in_sizes, int n_in,
                              void* d_out, int out_size, void* d_ws, size_t ws_size,
                              hipStream_t stream)
{
    const float* pf   = (const float*)d_in[0];
    const float* img  = (const float*)d_in[1];
    const float* fc2w = (const float*)d_in[2];
    const float* fc2b = (const float*)d_in[3];
    const float* cw   = (const float*)d_in[4];
    const float* cb   = (const float*)d_in[5];
    const float* g    = (const float*)d_in[6];
    const float* be   = (const float*)d_in[7];
    const float* mu   = (const float*)d_in[8];
    const float* var  = (const float*)d_in[9];
    float* out = (float*)d_out;

    // ws layout: EXACTLY the proven footprint (16,842,752 B).
    // imgT (4 MB, only live until fc2) ALIASES the fus region (8 MB) — zero
    // runs after fc2 and overwrites it.
    float* fus   = (float*)d_ws;                              // 8 MB
    float* zrsum = fus + (size_t)NB * NTOK * 256;             // 32 KB
    float* zcsum = zrsum + NB * NTOK;                         // 32 KB
    bf16_t* pfC = (bf16_t*)(zcsum + NB * NTOK);               // 2 MB
    bf16_t* pfT = pfC + (size_t)NB * PCH * NTOK;              // 2 MB
    bf16_t* riC = pfT + (size_t)NB * NTOK * PCH;              // 2 MB
    bf16_t* riT = riC + (size_t)NB * PCH * NTOK;              // 2 MB
    bf16_t* imgT = (bf16_t*)fus;                              // 4 MB alias

    pack_pf    <<<dim3(64, 2, NB),  256, 0, stream>>>(pf, pfC, pfT);
    pack_img   <<<dim3(64, 4, NB),  256, 0, stream>>>(img, imgT);
    fc2_mfma   <<<dim3(64, 2, NB),  256, 0, stream>>>(imgT, fc2w, fc2b, riC, riT);
    // zero fus + zsums: (2*4096*256 + 2*2*4096) floats = 528384 float4
    zero_kernel<<<dim3(2064), 256, 0, stream>>>((float4*)d_ws);
    stats_mfma <<<dim3(64, NB, 4),  256, 0, stream>>>(pfT, riT, zrsum, zcsum);
    attn_mfma  <<<dim3(64, NB, 8),  256, 0, stream>>>(pfT, riT, pfC, riC, zrsum, zcsum, fus);
    conv_mfma  <<<dim3(64, 2, NB),  256, 0, stream>>>(fus, cw, cb, g, be, mu, var, out);
}

// Round 14
// 213.496 us; speedup vs baseline: 1.5538x; 1.0029x over previous
//
#include <hip/hip_runtime.h>
#include <math.h>

// Problem constants
#define NTOK 4096
#define PCH  128
#define ICH  256
#define OCH  128
#define NB   2
#define SCALEF 0.08838834764831845f   // 1/sqrt(128)

typedef __bf16 bf16_t;
typedef __attribute__((ext_vector_type(8))) __bf16 bf16x8;
typedef __attribute__((ext_vector_type(4))) __bf16 bf16x4;
typedef __attribute__((ext_vector_type(4))) float floatx4;

#define LDK 136   // padded row length (bf16) for k=128 tiles
#define LDJ 72    // padded row length (bf16) for j=64 Es tiles

// LDS-only barrier: waits ds-ops (lgkmcnt) but does NOT drain in-flight
// global loads (vmcnt) — __syncthreads would. Loop's cross-wave traffic is
// LDS-only (Es), so vmcnt drain is semantically unnecessary.
#define LDS_BARRIER() asm volatile("s_waitcnt lgkmcnt(0)\n\ts_barrier" ::: "memory")

// ---------------------------------------------------------------------------
// K-1: zero fus (8 MB) + zsum buffers (64 KB) — contiguous at ws start.
// Runs AFTER fc2 (imgT aliases the fus region and is dead by then).
// ---------------------------------------------------------------------------
__global__ __launch_bounds__(256) void zero_kernel(float4* __restrict__ p)
{
    p[(size_t)blockIdx.x * 256 + threadIdx.x] = float4{0.f, 0.f, 0.f, 0.f};
}

// ---------------------------------------------------------------------------
// K0a: pack pf -> pfC (bf16 channel-major) + pfT (bf16 token-major)
// ---------------------------------------------------------------------------
__global__ __launch_bounds__(256) void pack_pf(const float* __restrict__ pf,
                                               bf16_t* __restrict__ pfC,
                                               bf16_t* __restrict__ pfT)
{
    __shared__ float Ls[64][65];
    const int t = threadIdx.x;
    const int n0 = blockIdx.x * 64, d0 = blockIdx.y * 64, b = blockIdx.z;
    const float* src = pf + ((size_t)(b * PCH + d0)) * NTOK + n0;
#pragma unroll
    for (int p = 0; p < 4; p++) {
        int d = p * 16 + (t >> 4), c = t & 15;
        float4 v = *(const float4*)&src[d * NTOK + c * 4];
        Ls[d][c * 4 + 0] = v.x; Ls[d][c * 4 + 1] = v.y;
        Ls[d][c * 4 + 2] = v.z; Ls[d][c * 4 + 3] = v.w;
        bf16x4 o = { (bf16_t)v.x, (bf16_t)v.y, (bf16_t)v.z, (bf16_t)v.w };
        *(bf16x4*)&pfC[((size_t)(b * PCH + d0 + d)) * NTOK + n0 + c * 4] = o;
    }
    __syncthreads();
#pragma unroll
    for (int p = 0; p < 2; p++) {
        int n = p * 32 + (t >> 3), c = t & 7;
        bf16x8 o;
#pragma unroll
        for (int k = 0; k < 8; k++) o[k] = (bf16_t)Ls[c * 8 + k][n];
        *(bf16x8*)&pfT[((size_t)(b * NTOK + n0 + n)) * PCH + d0 + c * 8] = o;
    }
}

// ---------------------------------------------------------------------------
// K0b: pack img (f32 channel-major [b][c][n]) -> imgT bf16 token-major
// ---------------------------------------------------------------------------
__global__ __launch_bounds__(256) void pack_img(const float* __restrict__ img,
                                                bf16_t* __restrict__ imgT)
{
    __shared__ float Ls[64][65];
    const int t = threadIdx.x;
    const int n0 = blockIdx.x * 64, c0 = blockIdx.y * 64, b = blockIdx.z;
    const float* src = img + ((size_t)(b * ICH + c0)) * NTOK + n0;
#pragma unroll
    for (int p = 0; p < 4; p++) {
        int d = p * 16 + (t >> 4), c = t & 15;
        float4 v = *(const float4*)&src[d * NTOK + c * 4];
        Ls[d][c * 4 + 0] = v.x; Ls[d][c * 4 + 1] = v.y;
        Ls[d][c * 4 + 2] = v.z; Ls[d][c * 4 + 3] = v.w;
    }
    __syncthreads();
#pragma unroll
    for (int p = 0; p < 2; p++) {
        int n = p * 32 + (t >> 3), c = t & 7;
        bf16x8 o;
#pragma unroll
        for (int k = 0; k < 8; k++) o[k] = (bf16_t)Ls[c * 8 + k][n];
        *(bf16x8*)&imgT[((size_t)(b * NTOK + n0 + n)) * ICH + c0 + c * 8] = o;
    }
}

// ---------------------------------------------------------------------------
// K1: fc2 (MFMA) — ri[p][n] = sum_c w[p][c]*img[c][n] + bias[p]
// ---------------------------------------------------------------------------
__global__ __launch_bounds__(256) void fc2_mfma(const bf16_t* __restrict__ imgT,
                                                const float* __restrict__ w,
                                                const float* __restrict__ bias,
                                                bf16_t* __restrict__ riC,
                                                bf16_t* __restrict__ riT)
{
    const int t = threadIdx.x;
    const int n0 = blockIdx.x * 64, pbase = blockIdx.y * 64, b = blockIdx.z;
    const int lane = t & 63, wv = t >> 6, tx = lane & 15, q = lane >> 4;
    const int n = n0 + wv * 16 + tx;
    const bf16_t* trow = imgT + ((size_t)(b * NTOK + n)) * ICH;

    floatx4 acc[4];
#pragma unroll
    for (int ot = 0; ot < 4; ot++) acc[ot] = (floatx4){0.f, 0.f, 0.f, 0.f};

#pragma unroll
    for (int s = 0; s < 8; s++) {
        bf16x8 bf = *(const bf16x8*)&trow[s * 32 + q * 8];
#pragma unroll
        for (int ot = 0; ot < 4; ot++) {
            const float* wr = w + (size_t)(pbase + ot * 16 + tx) * ICH + s * 32 + q * 8;
            float4 x0 = *(const float4*)wr;
            float4 x1 = *(const float4*)(wr + 4);
            bf16x8 af;
            af[0] = (bf16_t)x0.x; af[1] = (bf16_t)x0.y; af[2] = (bf16_t)x0.z; af[3] = (bf16_t)x0.w;
            af[4] = (bf16_t)x1.x; af[5] = (bf16_t)x1.y; af[6] = (bf16_t)x1.z; af[7] = (bf16_t)x1.w;
            acc[ot] = __builtin_amdgcn_mfma_f32_16x16x32_bf16(af, bf, acc[ot], 0, 0, 0);
        }
    }

#pragma unroll
    for (int ot = 0; ot < 4; ot++) {
        bf16x4 tv;
#pragma unroll
        for (int r = 0; r < 4; r++) {
            const int p = pbase + ot * 16 + q * 4 + r;
            float v = acc[ot][r] + bias[p];
            tv[r] = (bf16_t)v;
            riC[((size_t)(b * PCH + p)) * NTOK + n] = (bf16_t)v;
        }
        *(bf16x4*)&riT[((size_t)(b * NTOK + n)) * PCH + pbase + ot * 16 + q * 4] = tv;
    }
}

// ---------------------------------------------------------------------------
// K2: stats v5 (proven) — one pass over E = exp(scale * pf_i . ri_j):
//   zr[i] += sum_j E[i,j],  zc[j] += sum_i E[i,j]
// ---------------------------------------------------------------------------
__global__ __launch_bounds__(256, 4) void stats_mfma(const bf16_t* __restrict__ pfT,
                                                     const bf16_t* __restrict__ riT,
                                                     float* __restrict__ zr,
                                                     float* __restrict__ zc)
{
    __shared__ bf16_t As[64 * LDK];
    __shared__ float zacc[1024];
    const int b = blockIdx.y, t = threadIdx.x;
    const int js = blockIdx.z;
    const bf16_t* At = pfT + (size_t)b * NTOK * PCH;
    const bf16_t* Bt = riT + (size_t)b * NTOK * PCH;
    float* zrow = zr + (size_t)b * NTOK;
    float* zcol = zc + (size_t)b * NTOK;
    const int lane = t & 63, w = t >> 6, tx = lane & 15, q = lane >> 4;
    const int i0 = blockIdx.x * 64;
    const int jbase = js * 1024;
    const int sr = t >> 4, sc = t & 15;
    const bf16_t* Brow = Bt + (size_t)(jbase + w * 16 + tx) * PCH;

    bf16x8 bcur[4];
#pragma unroll
    for (int s = 0; s < 4; s++)
        bcur[s] = *(const bf16x8*)&Brow[s * 32 + q * 8];
#pragma unroll
    for (int p = 0; p < 4; p++) {
        int i = p * 16 + sr;
        *(uint4*)&As[i * LDK + sc * 8] = *(const uint4*)&At[((size_t)(i0 + i)) * PCH + sc * 8];
    }
    __syncthreads();
    bf16x8 af[4][4];
#pragma unroll
    for (int mt = 0; mt < 4; mt++)
#pragma unroll
        for (int s = 0; s < 4; s++)
            af[mt][s] = *(bf16x8*)&As[(mt * 16 + tx) * LDK + s * 32 + q * 8];

    float racc[4] = {0.f, 0.f, 0.f, 0.f};
    for (int jt = 0; jt < 16; jt++) {
        __builtin_amdgcn_s_barrier();            // pacing only
        floatx4 sacc[4];
#pragma unroll
        for (int mt = 0; mt < 4; mt++) {
            sacc[mt] = (floatx4){0.f, 0.f, 0.f, 0.f};
#pragma unroll
            for (int s = 0; s < 4; s++)
                sacc[mt] = __builtin_amdgcn_mfma_f32_16x16x32_bf16(bcur[s], af[mt][s], sacc[mt], 0, 0, 0);
        }
        if (jt < 15) {
            const bf16_t* bn = Brow + (size_t)(jt + 1) * 64 * PCH;
#pragma unroll
            for (int s = 0; s < 4; s++)
                bcur[s] = *(const bf16x8*)&bn[s * 32 + q * 8];
        }

        float ctmp[4] = {0.f, 0.f, 0.f, 0.f};
#pragma unroll
        for (int mt = 0; mt < 4; mt++)
#pragma unroll
            for (int r = 0; r < 4; r++) {
                float e = __expf(sacc[mt][r] * SCALEF);
                racc[mt] += e;
                ctmp[r]  += e;
            }
#pragma unroll
        for (int r = 0; r < 4; r++) {
            float v = ctmp[r];
            v += __shfl_xor(v, 1); v += __shfl_xor(v, 2);
            v += __shfl_xor(v, 4); v += __shfl_xor(v, 8);
            if (tx == 0) zacc[jt * 64 + w * 16 + q * 4 + r] = v;
        }
    }
#pragma unroll
    for (int mt = 0; mt < 4; mt++) {
        float v = racc[mt];
        v += __shfl_xor(v, 16);
        v += __shfl_xor(v, 32);
        if (q == 0) atomicAdd(&zrow[i0 + mt * 16 + tx], v);
    }
    __syncthreads();
#pragma unroll
    for (int k = 0; k < 4; k++)
        atomicAdd(&zcol[jbase + k * 256 + t], zacc[k * 256 + t]);
}

// ---------------------------------------------------------------------------
// K3: attn — R10 body; SINGLE change: in-loop __syncthreads -> LDS_BARRIER
// (lgkmcnt(0)+s_barrier, no vmcnt drain). Cross-wave traffic at that barrier
// is LDS-only (Es), so global prefetches may legally stay in flight —
// removes the all-waves vmcnt(0) drain stall (m97/s02 pattern).
// ---------------------------------------------------------------------------
__global__ __launch_bounds__(256, 3) void attn_mfma(const bf16_t* __restrict__ pfT,
                                                    const bf16_t* __restrict__ riT,
                                                    const bf16_t* __restrict__ pfC,
                                                    const bf16_t* __restrict__ riC,
                                                    const float* __restrict__ zrsum,
                                                    const float* __restrict__ zcsum,
                                                    float* __restrict__ fus)
{
    __shared__ bf16_t As[64 * LDK];
    __shared__ bf16_t Es[2][64 * LDJ];
    const int b = blockIdx.y, t = threadIdx.x;
    const int mode = blockIdx.z >> 2, js = blockIdx.z & 3;
    const bf16_t* At = (mode == 0 ? pfT : riT) + (size_t)b * NTOK * PCH;
    const bf16_t* Bt = (mode == 0 ? riT : pfT) + (size_t)b * NTOK * PCH;
    const bf16_t* Vc = (mode == 0 ? pfC : riC) + (size_t)b * PCH * NTOK;
    const float* wsum = (mode == 0 ? zcsum : zrsum) + (size_t)b * NTOK;
    const int lane = t & 63, w = t >> 6, tx = lane & 15, q = lane >> 4;
    const int i0 = blockIdx.x * 64;
    const int jbase = js * 1024;
    const int sr = t >> 4, sc = t & 15;
    const bf16_t* Brow = Bt + (size_t)(jbase + w * 16 + tx) * PCH;

    bf16x8 bcur[4];
#pragma unroll
    for (int s = 0; s < 4; s++)
        bcur[s] = *(const bf16x8*)&Brow[s * 32 + q * 8];
    bf16x8 vcur[2][2];
#pragma unroll
    for (int nt = 0; nt < 2; nt++)
#pragma unroll
        for (int s = 0; s < 2; s++)
            vcur[nt][s] = *(const bf16x8*)&Vc[((size_t)(w * 32 + nt * 16 + tx)) * NTOK + jbase + s * 32 + q * 8];
    float4 wv = *(const float4*)&wsum[jbase + w * 16 + q * 4];
    float4 wr4 = {1.f / wv.x, 1.f / wv.y, 1.f / wv.z, 1.f / wv.w};

#pragma unroll
    for (int p = 0; p < 4; p++) {
        int i = p * 16 + sr;
        *(uint4*)&As[i * LDK + sc * 8] = *(const uint4*)&At[((size_t)(i0 + i)) * PCH + sc * 8];
    }
    __syncthreads();
    bf16x8 af[4][4];
#pragma unroll
    for (int mt = 0; mt < 4; mt++)
#pragma unroll
        for (int s = 0; s < 4; s++)
            af[mt][s] = *(bf16x8*)&As[(mt * 16 + tx) * LDK + s * 32 + q * 8];

    floatx4 outacc[4][2];
#pragma unroll
    for (int mt = 0; mt < 4; mt++)
#pragma unroll
        for (int nt = 0; nt < 2; nt++)
            outacc[mt][nt] = (floatx4){0.f, 0.f, 0.f, 0.f};

    for (int jt = 0; jt < 16; jt++) {
        const int cur = jt & 1;
        const int j0 = jbase + jt * 64;

        floatx4 sacc[4];
#pragma unroll
        for (int mt = 0; mt < 4; mt++) {
            sacc[mt] = (floatx4){0.f, 0.f, 0.f, 0.f};
#pragma unroll
            for (int s = 0; s < 4; s++)
                sacc[mt] = __builtin_amdgcn_mfma_f32_16x16x32_bf16(bcur[s], af[mt][s], sacc[mt], 0, 0, 0);
        }
        if (jt < 15) {
            const bf16_t* bn = Brow + (size_t)(jt + 1) * 64 * PCH;
#pragma unroll
            for (int s = 0; s < 4; s++)
                bcur[s] = *(const bf16x8*)&bn[s * 32 + q * 8];
        }

#pragma unroll
        for (int mt = 0; mt < 4; mt++) {
            bf16x4 ev;
#pragma unroll
            for (int r = 0; r < 4; r++)
                ev[r] = (bf16_t)(__expf(sacc[mt][r] * SCALEF) * ((const float*)&wr4)[r]);
            *(bf16x4*)&Es[cur][(mt * 16 + tx) * LDJ + w * 16 + q * 4] = ev;
        }
        float4 wnv;
        if (jt < 15)
            wnv = *(const float4*)&wsum[j0 + 64 + w * 16 + q * 4];

        LDS_BARRIER();                           // lgkmcnt(0)+s_barrier, NO vmcnt drain

        bf16x8 ef[4][2];
#pragma unroll
        for (int mt = 0; mt < 4; mt++)
#pragma unroll
            for (int s = 0; s < 2; s++)
                ef[mt][s] = *(bf16x8*)&Es[cur][(mt * 16 + tx) * LDJ + s * 32 + q * 8];
#pragma unroll
        for (int nt = 0; nt < 2; nt++)
#pragma unroll
            for (int s = 0; s < 2; s++)
#pragma unroll
                for (int mt = 0; mt < 4; mt++)
                    outacc[mt][nt] = __builtin_amdgcn_mfma_f32_16x16x32_bf16(ef[mt][s], vcur[nt][s], outacc[mt][nt], 0, 0, 0);

        if (jt < 15) {
#pragma unroll
            for (int nt = 0; nt < 2; nt++)
#pragma unroll
                for (int s = 0; s < 2; s++)
                    vcur[nt][s] = *(const bf16x8*)&Vc[((size_t)(w * 32 + nt * 16 + tx)) * NTOK + (j0 + 64) + s * 32 + q * 8];
            wr4 = (float4){1.f / wnv.x, 1.f / wnv.y, 1.f / wnv.z, 1.f / wnv.w};
        }
    }

    float* fo = fus + ((size_t)(b * NTOK + i0)) * 256 + mode * 128 + w * 32;
#pragma unroll
    for (int mt = 0; mt < 4; mt++)
#pragma unroll
        for (int nt = 0; nt < 2; nt++)
#pragma unroll
            for (int r = 0; r < 4; r++)
                atomicAdd(&fo[(mt * 16 + q * 4 + r) * 256 + nt * 16 + tx], outacc[mt][nt][r]);
}

// ---------------------------------------------------------------------------
// K4: conv (MFMA) — out[o][n] = relu(bn(sum_c cw[o][c]*fus[n][c] + cb))
// ---------------------------------------------------------------------------
__global__ __launch_bounds__(256) void conv_mfma(const float* __restrict__ fus,
                                                 const float* __restrict__ cw,
                                                 const float* __restrict__ cb,
                                                 const float* __restrict__ g,
                                                 const float* __restrict__ be,
                                                 const float* __restrict__ mu,
                                                 const float* __restrict__ var,
                                                 float* __restrict__ out)
{
    const int t = threadIdx.x;
    const int n0 = blockIdx.x * 64, obase = blockIdx.y * 64, b = blockIdx.z;
    const int lane = t & 63, wv = t >> 6, tx = lane & 15, q = lane >> 4;
    const int n = n0 + wv * 16 + tx;
    const float* frow = fus + ((size_t)(b * NTOK + n)) * 256;

    floatx4 acc[4];
#pragma unroll
    for (int ot = 0; ot < 4; ot++) acc[ot] = (floatx4){0.f, 0.f, 0.f, 0.f};

#pragma unroll
    for (int s = 0; s < 8; s++) {
        float4 f0 = *(const float4*)&frow[s * 32 + q * 8];
        float4 f1 = *(const float4*)&frow[s * 32 + q * 8 + 4];
        bf16x8 bf;
        bf[0] = (bf16_t)f0.x; bf[1] = (bf16_t)f0.y; bf[2] = (bf16_t)f0.z; bf[3] = (bf16_t)f0.w;
        bf[4] = (bf16_t)f1.x; bf[5] = (bf16_t)f1.y; bf[6] = (bf16_t)f1.z; bf[7] = (bf16_t)f1.w;
#pragma unroll
        for (int ot = 0; ot < 4; ot++) {
            const float* wr = cw + (size_t)(obase + ot * 16 + tx) * 256 + s * 32 + q * 8;
            float4 x0 = *(const float4*)wr;
            float4 x1 = *(const float4*)(wr + 4);
            bf16x8 af;
            af[0] = (bf16_t)x0.x; af[1] = (bf16_t)x0.y; af[2] = (bf16_t)x0.z; af[3] = (bf16_t)x0.w;
            af[4] = (bf16_t)x1.x; af[5] = (bf16_t)x1.y; af[6] = (bf16_t)x1.z; af[7] = (bf16_t)x1.w;
            acc[ot] = __builtin_amdgcn_mfma_f32_16x16x32_bf16(af, bf, acc[ot], 0, 0, 0);
        }
    }

#pragma unroll
    for (int ot = 0; ot < 4; ot++)
#pragma unroll
        for (int r = 0; r < 4; r++) {
            const int o = obase + ot * 16 + q * 4 + r;
            const float sc = g[o] * rsqrtf(var[o] + 1e-5f);
            const float b0 = be[o] + (cb[o] - mu[o]) * sc;
            float y = acc[ot][r] * sc + b0;
            out[((size_t)(b * OCH + o)) * NTOK + n] = fmaxf(y, 0.f);
        }
}

// ---------------------------------------------------------------------------
extern "C" void kernel_launch(void* const* d_in, const int* in_sizes, int n_in,
                              void* d_out, int out_size, void* d_ws, size_t ws_size,
                              hipStream_t stream)
{
    const float* pf   = (const float*)d_in[0];
    const float* img  = (const float*)d_in[1];
    const float* fc2w = (const float*)d_in[2];
    const float* fc2b = (const float*)d_in[3];
    const float* cw   = (const float*)d_in[4];
    const float* cb   = (const float*)d_in[5];
    const float* g    = (const float*)d_in[6];
    const float* be   = (const float*)d_in[7];
    const float* mu   = (const float*)d_in[8];
    const float* var  = (const float*)d_in[9];
    float* out = (float*)d_out;

    // ws layout: proven footprint (16,842,752 B). imgT aliases fus region.
    float* fus   = (float*)d_ws;                              // 8 MB
    float* zrsum = fus + (size_t)NB * NTOK * 256;             // 32 KB
    float* zcsum = zrsum + NB * NTOK;                         // 32 KB
    bf16_t* pfC = (bf16_t*)(zcsum + NB * NTOK);               // 2 MB
    bf16_t* pfT = pfC + (size_t)NB * PCH * NTOK;              // 2 MB
    bf16_t* riC = pfT + (size_t)NB * NTOK * PCH;              // 2 MB
    bf16_t* riT = riC + (size_t)NB * PCH * NTOK;              // 2 MB
    bf16_t* imgT = (bf16_t*)fus;                              // 4 MB alias

    pack_pf    <<<dim3(64, 2, NB),  256, 0, stream>>>(pf, pfC, pfT);
    pack_img   <<<dim3(64, 4, NB),  256, 0, stream>>>(img, imgT);
    fc2_mfma   <<<dim3(64, 2, NB),  256, 0, stream>>>(imgT, fc2w, fc2b, riC, riT);
    zero_kernel<<<dim3(2064), 256, 0, stream>>>((float4*)d_ws);
    stats_mfma <<<dim3(64, NB, 4),  256, 0, stream>>>(pfT, riT, zrsum, zcsum);
    attn_mfma  <<<dim3(64, NB, 8),  256, 0, stream>>>(pfT, riT, pfC, riC, zrsum, zcsum, fus);
    conv_mfma  <<<dim3(64, 2, NB),  256, 0, stream>>>(fus, cw, cb, g, be, mu, var, out);
}

// Round 15
// 211.477 us; speedup vs baseline: 1.5686x; 1.0095x over previous
//
#include <hip/hip_runtime.h>
#include <math.h>

// Problem constants
#define NTOK 4096
#define PCH  128
#define ICH  256
#define OCH  128
#define NB   2
#define SCALEF 0.08838834764831845f   // 1/sqrt(128)

typedef __bf16 bf16_t;
typedef __attribute__((ext_vector_type(8))) __bf16 bf16x8;
typedef __attribute__((ext_vector_type(4))) __bf16 bf16x4;
typedef __attribute__((ext_vector_type(4))) float floatx4;

#define LDK 136   // padded row length (bf16) for k=128 tiles
#define LDJ 72    // padded row length (bf16) for j=64 Es tiles

// ---------------------------------------------------------------------------
// K0: merged pack — y<2: pf -> pfC + pfT;  y>=2: img -> imgT (token-major)
// ---------------------------------------------------------------------------
__global__ __launch_bounds__(256) void pack_all(const float* __restrict__ pf,
                                                const float* __restrict__ img,
                                                bf16_t* __restrict__ pfC,
                                                bf16_t* __restrict__ pfT,
                                                bf16_t* __restrict__ imgT)
{
    __shared__ float Ls[64][65];
    const int t = threadIdx.x;
    const int n0 = blockIdx.x * 64, b = blockIdx.z;
    const bool ispf = blockIdx.y < 2;
    const int d0 = ispf ? blockIdx.y * 64 : (blockIdx.y - 2) * 64;
    const float* src = (ispf ? pf + ((size_t)(b * PCH + d0)) * NTOK
                             : img + ((size_t)(b * ICH + d0)) * NTOK) + n0;
#pragma unroll
    for (int p = 0; p < 4; p++) {
        int d = p * 16 + (t >> 4), c = t & 15;
        float4 v = *(const float4*)&src[d * NTOK + c * 4];
        Ls[d][c * 4 + 0] = v.x; Ls[d][c * 4 + 1] = v.y;
        Ls[d][c * 4 + 2] = v.z; Ls[d][c * 4 + 3] = v.w;
        if (ispf) {
            bf16x4 o = { (bf16_t)v.x, (bf16_t)v.y, (bf16_t)v.z, (bf16_t)v.w };
            *(bf16x4*)&pfC[((size_t)(b * PCH + d0 + d)) * NTOK + n0 + c * 4] = o;
        }
    }
    __syncthreads();
#pragma unroll
    for (int p = 0; p < 2; p++) {
        int n = p * 32 + (t >> 3), c = t & 7;
        bf16x8 o;
#pragma unroll
        for (int k = 0; k < 8; k++) o[k] = (bf16_t)Ls[c * 8 + k][n];
        if (ispf)
            *(bf16x8*)&pfT[((size_t)(b * NTOK + n0 + n)) * PCH + d0 + c * 8] = o;
        else
            *(bf16x8*)&imgT[((size_t)(b * NTOK + n0 + n)) * ICH + d0 + c * 8] = o;
    }
}

// ---------------------------------------------------------------------------
// K1: fc2 (MFMA) — ri[p][n] = sum_c w[p][c]*img[c][n] + bias[p]
// Also zeroes the zsum buffers (16384 floats) in its prologue (fc2 completes
// before stats starts -> stream-ordered, no extra launch).
// ---------------------------------------------------------------------------
__global__ __launch_bounds__(256) void fc2_mfma(const bf16_t* __restrict__ imgT,
                                                const float* __restrict__ w,
                                                const float* __restrict__ bias,
                                                bf16_t* __restrict__ riC,
                                                bf16_t* __restrict__ riT,
                                                float* __restrict__ zsums)
{
    const int t = threadIdx.x;
    if (blockIdx.y == 0 && blockIdx.z == 0)
        zsums[blockIdx.x * 256 + t] = 0.f;       // 64 blocks x 256 = 16384 floats

    const int n0 = blockIdx.x * 64, pbase = blockIdx.y * 64, b = blockIdx.z;
    const int lane = t & 63, wv = t >> 6, tx = lane & 15, q = lane >> 4;
    const int n = n0 + wv * 16 + tx;
    const bf16_t* trow = imgT + ((size_t)(b * NTOK + n)) * ICH;

    floatx4 acc[4];
#pragma unroll
    for (int ot = 0; ot < 4; ot++) acc[ot] = (floatx4){0.f, 0.f, 0.f, 0.f};

#pragma unroll
    for (int s = 0; s < 8; s++) {
        bf16x8 bf = *(const bf16x8*)&trow[s * 32 + q * 8];
#pragma unroll
        for (int ot = 0; ot < 4; ot++) {
            const float* wr = w + (size_t)(pbase + ot * 16 + tx) * ICH + s * 32 + q * 8;
            float4 x0 = *(const float4*)wr;
            float4 x1 = *(const float4*)(wr + 4);
            bf16x8 af;
            af[0] = (bf16_t)x0.x; af[1] = (bf16_t)x0.y; af[2] = (bf16_t)x0.z; af[3] = (bf16_t)x0.w;
            af[4] = (bf16_t)x1.x; af[5] = (bf16_t)x1.y; af[6] = (bf16_t)x1.z; af[7] = (bf16_t)x1.w;
            acc[ot] = __builtin_amdgcn_mfma_f32_16x16x32_bf16(af, bf, acc[ot], 0, 0, 0);
        }
    }

#pragma unroll
    for (int ot = 0; ot < 4; ot++) {
        bf16x4 tv;
#pragma unroll
        for (int r = 0; r < 4; r++) {
            const int p = pbase + ot * 16 + q * 4 + r;
            float v = acc[ot][r] + bias[p];
            tv[r] = (bf16_t)v;
            riC[((size_t)(b * PCH + p)) * NTOK + n] = (bf16_t)v;
        }
        *(bf16x4*)&riT[((size_t)(b * NTOK + n)) * PCH + pbase + ot * 16 + q * 4] = tv;
    }
}

// ---------------------------------------------------------------------------
// K2: stats v5 + XCD swizzle + fus-zero prologue. 1D grid 512:
// xcd = blk&7, slot = blk>>3 (0..63); group g=xcd -> (b=g&1, js=g>>1);
// i0 = slot*64. All 64 blocks of one (b,js) share one XCD's L2 (B quarter
// 1 MB + A bands -> ~2 MB working set vs 4 MB L2).
// ---------------------------------------------------------------------------
__global__ __launch_bounds__(256, 4) void stats_mfma(const bf16_t* __restrict__ pfT,
                                                     const bf16_t* __restrict__ riT,
                                                     float* __restrict__ zr,
                                                     float* __restrict__ zc,
                                                     float* __restrict__ fus)
{
    __shared__ bf16_t As[64 * LDK];
    __shared__ float zacc[1024];
    const int t = threadIdx.x;
    const int blk = blockIdx.x;

    { // zero fus: 512 blocks x 256 thr x 4 float4 = 2,097,152 floats exactly
        float4* f4 = (float4*)fus + ((size_t)blk * 256 + t) * 4;
        f4[0] = float4{0.f, 0.f, 0.f, 0.f};
        f4[1] = float4{0.f, 0.f, 0.f, 0.f};
        f4[2] = float4{0.f, 0.f, 0.f, 0.f};
        f4[3] = float4{0.f, 0.f, 0.f, 0.f};
    }

    const int g = blk & 7, slot = blk >> 3;      // XCD-aware decode
    const int b = g & 1, js = g >> 1;
    const bf16_t* At = pfT + (size_t)b * NTOK * PCH;
    const bf16_t* Bt = riT + (size_t)b * NTOK * PCH;
    float* zrow = zr + (size_t)b * NTOK;
    float* zcol = zc + (size_t)b * NTOK;
    const int lane = t & 63, w = t >> 6, tx = lane & 15, q = lane >> 4;
    const int i0 = slot * 64;
    const int jbase = js * 1024;
    const int sr = t >> 4, sc = t & 15;
    const bf16_t* Brow = Bt + (size_t)(jbase + w * 16 + tx) * PCH;

    bf16x8 bcur[4];
#pragma unroll
    for (int s = 0; s < 4; s++)
        bcur[s] = *(const bf16x8*)&Brow[s * 32 + q * 8];
#pragma unroll
    for (int p = 0; p < 4; p++) {
        int i = p * 16 + sr;
        *(uint4*)&As[i * LDK + sc * 8] = *(const uint4*)&At[((size_t)(i0 + i)) * PCH + sc * 8];
    }
    __syncthreads();
    bf16x8 af[4][4];
#pragma unroll
    for (int mt = 0; mt < 4; mt++)
#pragma unroll
        for (int s = 0; s < 4; s++)
            af[mt][s] = *(bf16x8*)&As[(mt * 16 + tx) * LDK + s * 32 + q * 8];

    float racc[4] = {0.f, 0.f, 0.f, 0.f};
    for (int jt = 0; jt < 16; jt++) {
        __builtin_amdgcn_s_barrier();            // pacing only
        floatx4 sacc[4];
#pragma unroll
        for (int mt = 0; mt < 4; mt++) {
            sacc[mt] = (floatx4){0.f, 0.f, 0.f, 0.f};
#pragma unroll
            for (int s = 0; s < 4; s++)
                sacc[mt] = __builtin_amdgcn_mfma_f32_16x16x32_bf16(bcur[s], af[mt][s], sacc[mt], 0, 0, 0);
        }
        if (jt < 15) {
            const bf16_t* bn = Brow + (size_t)(jt + 1) * 64 * PCH;
#pragma unroll
            for (int s = 0; s < 4; s++)
                bcur[s] = *(const bf16x8*)&bn[s * 32 + q * 8];
        }

        float ctmp[4] = {0.f, 0.f, 0.f, 0.f};
#pragma unroll
        for (int mt = 0; mt < 4; mt++)
#pragma unroll
            for (int r = 0; r < 4; r++) {
                float e = __expf(sacc[mt][r] * SCALEF);
                racc[mt] += e;
                ctmp[r]  += e;
            }
#pragma unroll
        for (int r = 0; r < 4; r++) {
            float v = ctmp[r];
            v += __shfl_xor(v, 1); v += __shfl_xor(v, 2);
            v += __shfl_xor(v, 4); v += __shfl_xor(v, 8);
            if (tx == 0) zacc[jt * 64 + w * 16 + q * 4 + r] = v;
        }
    }
#pragma unroll
    for (int mt = 0; mt < 4; mt++) {
        float v = racc[mt];
        v += __shfl_xor(v, 16);
        v += __shfl_xor(v, 32);
        if (q == 0) atomicAdd(&zrow[i0 + mt * 16 + tx], v);
    }
    __syncthreads();
#pragma unroll
    for (int k = 0; k < 4; k++)
        atomicAdd(&zcol[jbase + k * 256 + t], zacc[k * 256 + t]);
}

// ---------------------------------------------------------------------------
// K3: attn — R13 body (proven 80.5us, __syncthreads) + XCD swizzle.
// 1D grid 1024: xcd=blk&7, slot=blk>>3 (0..127); g = xcd*2 + (slot>>6)
// -> (b=g&1, z=g>>1); i0 = (slot&63)*64. XCD k serves z=k for both batches.
// ---------------------------------------------------------------------------
__global__ __launch_bounds__(256, 3) void attn_mfma(const bf16_t* __restrict__ pfT,
                                                    const bf16_t* __restrict__ riT,
                                                    const bf16_t* __restrict__ pfC,
                                                    const bf16_t* __restrict__ riC,
                                                    const float* __restrict__ zrsum,
                                                    const float* __restrict__ zcsum,
                                                    float* __restrict__ fus)
{
    __shared__ bf16_t As[64 * LDK];
    __shared__ bf16_t Es[2][64 * LDJ];
    const int t = threadIdx.x;
    const int blk = blockIdx.x;
    const int g = (blk & 7) * 2 + ((blk >> 3) >> 6);   // XCD-aware decode
    const int slot = (blk >> 3) & 63;
    const int b = g & 1, z = g >> 1;
    const int mode = z >> 2, js = z & 3;
    const bf16_t* At = (mode == 0 ? pfT : riT) + (size_t)b * NTOK * PCH;
    const bf16_t* Bt = (mode == 0 ? riT : pfT) + (size_t)b * NTOK * PCH;
    const bf16_t* Vc = (mode == 0 ? pfC : riC) + (size_t)b * PCH * NTOK;
    const float* wsum = (mode == 0 ? zcsum : zrsum) + (size_t)b * NTOK;
    const int lane = t & 63, w = t >> 6, tx = lane & 15, q = lane >> 4;
    const int i0 = slot * 64;
    const int jbase = js * 1024;
    const int sr = t >> 4, sc = t & 15;
    const bf16_t* Brow = Bt + (size_t)(jbase + w * 16 + tx) * PCH;

    bf16x8 bcur[4];
#pragma unroll
    for (int s = 0; s < 4; s++)
        bcur[s] = *(const bf16x8*)&Brow[s * 32 + q * 8];
    bf16x8 vcur[2][2];
#pragma unroll
    for (int nt = 0; nt < 2; nt++)
#pragma unroll
        for (int s = 0; s < 2; s++)
            vcur[nt][s] = *(const bf16x8*)&Vc[((size_t)(w * 32 + nt * 16 + tx)) * NTOK + jbase + s * 32 + q * 8];
    float4 wv = *(const float4*)&wsum[jbase + w * 16 + q * 4];
    float4 wr4 = {1.f / wv.x, 1.f / wv.y, 1.f / wv.z, 1.f / wv.w};

#pragma unroll
    for (int p = 0; p < 4; p++) {
        int i = p * 16 + sr;
        *(uint4*)&As[i * LDK + sc * 8] = *(const uint4*)&At[((size_t)(i0 + i)) * PCH + sc * 8];
    }
    __syncthreads();
    bf16x8 af[4][4];
#pragma unroll
    for (int mt = 0; mt < 4; mt++)
#pragma unroll
        for (int s = 0; s < 4; s++)
            af[mt][s] = *(bf16x8*)&As[(mt * 16 + tx) * LDK + s * 32 + q * 8];

    floatx4 outacc[4][2];
#pragma unroll
    for (int mt = 0; mt < 4; mt++)
#pragma unroll
        for (int nt = 0; nt < 2; nt++)
            outacc[mt][nt] = (floatx4){0.f, 0.f, 0.f, 0.f};

    for (int jt = 0; jt < 16; jt++) {
        const int cur = jt & 1;
        const int j0 = jbase + jt * 64;

        floatx4 sacc[4];
#pragma unroll
        for (int mt = 0; mt < 4; mt++) {
            sacc[mt] = (floatx4){0.f, 0.f, 0.f, 0.f};
#pragma unroll
            for (int s = 0; s < 4; s++)
                sacc[mt] = __builtin_amdgcn_mfma_f32_16x16x32_bf16(bcur[s], af[mt][s], sacc[mt], 0, 0, 0);
        }
        if (jt < 15) {
            const bf16_t* bn = Brow + (size_t)(jt + 1) * 64 * PCH;
#pragma unroll
            for (int s = 0; s < 4; s++)
                bcur[s] = *(const bf16x8*)&bn[s * 32 + q * 8];
        }

#pragma unroll
        for (int mt = 0; mt < 4; mt++) {
            bf16x4 ev;
#pragma unroll
            for (int r = 0; r < 4; r++)
                ev[r] = (bf16_t)(__expf(sacc[mt][r] * SCALEF) * ((const float*)&wr4)[r]);
            *(bf16x4*)&Es[cur][(mt * 16 + tx) * LDJ + w * 16 + q * 4] = ev;
        }
        float4 wnv;
        if (jt < 15)
            wnv = *(const float4*)&wsum[j0 + 64 + w * 16 + q * 4];

        __syncthreads();

        bf16x8 ef[4][2];
#pragma unroll
        for (int mt = 0; mt < 4; mt++)
#pragma unroll
            for (int s = 0; s < 2; s++)
                ef[mt][s] = *(bf16x8*)&Es[cur][(mt * 16 + tx) * LDJ + s * 32 + q * 8];
#pragma unroll
        for (int nt = 0; nt < 2; nt++)
#pragma unroll
            for (int s = 0; s < 2; s++)
#pragma unroll
                for (int mt = 0; mt < 4; mt++)
                    outacc[mt][nt] = __builtin_amdgcn_mfma_f32_16x16x32_bf16(ef[mt][s], vcur[nt][s], outacc[mt][nt], 0, 0, 0);

        if (jt < 15) {
#pragma unroll
            for (int nt = 0; nt < 2; nt++)
#pragma unroll
                for (int s = 0; s < 2; s++)
                    vcur[nt][s] = *(const bf16x8*)&Vc[((size_t)(w * 32 + nt * 16 + tx)) * NTOK + (j0 + 64) + s * 32 + q * 8];
            wr4 = (float4){1.f / wnv.x, 1.f / wnv.y, 1.f / wnv.z, 1.f / wnv.w};
        }
    }

    float* fo = fus + ((size_t)(b * NTOK + i0)) * 256 + mode * 128 + w * 32;
#pragma unroll
    for (int mt = 0; mt < 4; mt++)
#pragma unroll
        for (int nt = 0; nt < 2; nt++)
#pragma unroll
            for (int r = 0; r < 4; r++)
                atomicAdd(&fo[(mt * 16 + q * 4 + r) * 256 + nt * 16 + tx], outacc[mt][nt][r]);
}

// ---------------------------------------------------------------------------
// K4: conv (MFMA) — out[o][n] = relu(bn(sum_c cw[o][c]*fus[n][c] + cb))
// ---------------------------------------------------------------------------
__global__ __launch_bounds__(256) void conv_mfma(const float* __restrict__ fus,
                                                 const float* __restrict__ cw,
                                                 const float* __restrict__ cb,
                                                 const float* __restrict__ g,
                                                 const float* __restrict__ be,
                                                 const float* __restrict__ mu,
                                                 const float* __restrict__ var,
                                                 float* __restrict__ out)
{
    const int t = threadIdx.x;
    const int n0 = blockIdx.x * 64, obase = blockIdx.y * 64, b = blockIdx.z;
    const int lane = t & 63, wv = t >> 6, tx = lane & 15, q = lane >> 4;
    const int n = n0 + wv * 16 + tx;
    const float* frow = fus + ((size_t)(b * NTOK + n)) * 256;

    floatx4 acc[4];
#pragma unroll
    for (int ot = 0; ot < 4; ot++) acc[ot] = (floatx4){0.f, 0.f, 0.f, 0.f};

#pragma unroll
    for (int s = 0; s < 8; s++) {
        float4 f0 = *(const float4*)&frow[s * 32 + q * 8];
        float4 f1 = *(const float4*)&frow[s * 32 + q * 8 + 4];
        bf16x8 bf;
        bf[0] = (bf16_t)f0.x; bf[1] = (bf16_t)f0.y; bf[2] = (bf16_t)f0.z; bf[3] = (bf16_t)f0.w;
        bf[4] = (bf16_t)f1.x; bf[5] = (bf16_t)f1.y; bf[6] = (bf16_t)f1.z; bf[7] = (bf16_t)f1.w;
#pragma unroll
        for (int ot = 0; ot < 4; ot++) {
            const float* wr = cw + (size_t)(obase + ot * 16 + tx) * 256 + s * 32 + q * 8;
            float4 x0 = *(const float4*)wr;
            float4 x1 = *(const float4*)(wr + 4);
            bf16x8 af;
            af[0] = (bf16_t)x0.x; af[1] = (bf16_t)x0.y; af[2] = (bf16_t)x0.z; af[3] = (bf16_t)x0.w;
            af[4] = (bf16_t)x1.x; af[5] = (bf16_t)x1.y; af[6] = (bf16_t)x1.z; af[7] = (bf16_t)x1.w;
            acc[ot] = __builtin_amdgcn_mfma_f32_16x16x32_bf16(af, bf, acc[ot], 0, 0, 0);
        }
    }

#pragma unroll
    for (int ot = 0; ot < 4; ot++)
#pragma unroll
        for (int r = 0; r < 4; r++) {
            const int o = obase + ot * 16 + q * 4 + r;
            const float sc = g[o] * rsqrtf(var[o] + 1e-5f);
            const float b0 = be[o] + (cb[o] - mu[o]) * sc;
            float y = acc[ot][r] * sc + b0;
            out[((size_t)(b * OCH + o)) * NTOK + n] = fmaxf(y, 0.f);
        }
}

// ---------------------------------------------------------------------------
extern "C" void kernel_launch(void* const* d_in, const int* in_sizes, int n_in,
                              void* d_out, int out_size, void* d_ws, size_t ws_size,
                              hipStream_t stream)
{
    const float* pf   = (const float*)d_in[0];
    const float* img  = (const float*)d_in[1];
    const float* fc2w = (const float*)d_in[2];
    const float* fc2b = (const float*)d_in[3];
    const float* cw   = (const float*)d_in[4];
    const float* cb   = (const float*)d_in[5];
    const float* g    = (const float*)d_in[6];
    const float* be   = (const float*)d_in[7];
    const float* mu   = (const float*)d_in[8];
    const float* var  = (const float*)d_in[9];
    float* out = (float*)d_out;

    // ws layout: proven footprint (16,842,752 B). imgT aliases fus region
    // (dead after fc2; fus is zeroed inside stats which runs after fc2).
    float* fus   = (float*)d_ws;                              // 8 MB
    float* zrsum = fus + (size_t)NB * NTOK * 256;             // 32 KB
    float* zcsum = zrsum + NB * NTOK;                         // 32 KB (contiguous after zrsum)
    bf16_t* pfC = (bf16_t*)(zcsum + NB * NTOK);               // 2 MB
    bf16_t* pfT = pfC + (size_t)NB * PCH * NTOK;              // 2 MB
    bf16_t* riC = pfT + (size_t)NB * NTOK * PCH;              // 2 MB
    bf16_t* riT = riC + (size_t)NB * PCH * NTOK;              // 2 MB
    bf16_t* imgT = (bf16_t*)fus;                              // 4 MB alias

    pack_all  <<<dim3(64, 6, NB), 256, 0, stream>>>(pf, img, pfC, pfT, imgT);
    fc2_mfma  <<<dim3(64, 2, NB), 256, 0, stream>>>(imgT, fc2w, fc2b, riC, riT, zrsum);
    stats_mfma<<<dim3(512),       256, 0, stream>>>(pfT, riT, zrsum, zcsum, fus);
    attn_mfma <<<dim3(1024),      256, 0, stream>>>(pfT, riT, pfC, riC, zrsum, zcsum, fus);
    conv_mfma <<<dim3(64, 2, NB), 256, 0, stream>>>(fus, cw, cb, g, be, mu, var, out);
}